// Round 9
// baseline (349.121 us; speedup 1.0000x reference)
//
#include <hip/hip_runtime.h>

// STN round 9: all weights LDS-staged (no global loads inside compute phases);
// conv2 + fc1 converted to f16-pair fdot2. Theory: rounds 4-8 were limited by
// the latency-serial global w2/fc1w loads inside single-wave phases, not by
// VALU instruction count (r5->r8 cut insts 40%, time unchanged).

typedef _Float16 half2_t __attribute__((ext_vector_type(2)));

static __device__ inline half2_t h2(uint32_t u) {
    union { uint32_t u; half2_t h; } cv; cv.u = u; return cv.h;
}
static __device__ inline uint32_t packh2(float a, float b) {
    union { half2_t h; uint32_t u; } cv;
    cv.h = (half2_t){(_Float16)a, (_Float16)b};
    return cv.u;
}

#if __has_builtin(__builtin_amdgcn_fdot2)
#define FDOT2(a, b, c) __builtin_amdgcn_fdot2((a), (b), (c), false)
#else
#define FDOT2(a, b, c) ((float)(a)[0] * (float)(b)[0] + (float)(a)[1] * (float)(b)[1] + (c))
#endif

__launch_bounds__(256, 4)
__global__ void stn_loc_kernel(
    const float* __restrict__ x,
    const float* __restrict__ w1, const float* __restrict__ b1,
    const float* __restrict__ w2, const float* __restrict__ b2,
    const float* __restrict__ fc1w, const float* __restrict__ fc1b,
    const float* __restrict__ fc2w, const float* __restrict__ fc2b,
    float* __restrict__ theta_ws)
{
    __shared__ __align__(16) _Float16 s_imgh[3 * 28 * 40];   // 6720 B, CHW f16, cols padded
    __shared__ __align__(16) uint32_t s_w1p[8 * 21 * 4];     // 2688 B, conv1 half2 kw-pairs
    __shared__ __align__(16) uint32_t s_h1p[4 * 11 * 12];    // 2112 B, pooled1 f16 c-pairs
    __shared__ __align__(16) uint32_t s_w2p[4 * 5 * 10 * 8]; // 6400 B, [(c2*5+kh)*10+o][kw8]
    __shared__ __align__(16) uint32_t s_fc1wp[32 * 49];      // 6272 B, f16 j-pairs, row pad 49
    __shared__ __align__(16) uint32_t s_h2p[64];             // 256 B, f16 halves of h2[90]
    __shared__ float s_fch[32];

    const int t = threadIdx.x;
    const int n = blockIdx.x;
    const float* img = x + (size_t)n * 2352;

    // ---- Stage A: all staging (image + every weight) -> LDS, cooperative.
    // zero pad cols 28..39 of image rows
    for (int idx = t; idx < 504; idx += 256) {
        const int cc = idx / 168;
        const int rem = idx - 168 * cc;
        const int hh = rem / 6;
        const int kk = rem - 6 * hh;
        ((uint32_t*)s_imgh)[(((cc * 28 + hh) * 40) + 28 + 2 * kk) >> 1] = 0u;
    }
    // image HWC fp32 -> LDS CHW f16
    for (int p = t; p < 784; p += 256) {
        const int h = p / 28, w = p - 28 * h;
        const float v0 = img[3 * p + 0];
        const float v1 = img[3 * p + 1];
        const float v2 = img[3 * p + 2];
        s_imgh[(0 * 28 + h) * 40 + w] = (_Float16)v0;
        s_imgh[(1 * 28 + h) * 40 + w] = (_Float16)v1;
        s_imgh[(2 * 28 + h) * 40 + w] = (_Float16)v2;
    }
    // conv1 weights -> half2 kw-pairs
    for (int idx = t; idx < 672; idx += 256) {
        const int o = idx / 84;  const int rem = idx - 84 * o;
        const int c = rem / 28;  const int r2 = rem - 28 * c;
        const int kh = r2 >> 2;  const int p = r2 & 3;
        const int k0 = 2 * p;
        const float* wbase = &w1[((o * 3 + c) * 7 + kh) * 7];
        const float wa = wbase[k0];
        const float wb = (k0 + 1 < 7) ? wbase[k0 + 1] : 0.0f;
        s_w1p[idx] = packh2(wa, wb);
    }
    // conv2 weights -> f16 channel-pairs: [(c2*5+kh)*10+o][kw pad 8]
    for (int k = t; k < 1600; k += 256) {
        const int kw = k & 7;
        const int r = k >> 3;           // (c2*5+kh)*10 + o
        const int o = r % 10;
        const int ck = r / 10;          // c2*5+kh
        const int kh = ck % 5;
        const int c2 = ck / 5;
        uint32_t v = 0;
        if (kw < 5) {
            const float wa = w2[((o * 8 + 2 * c2) * 5 + kh) * 5 + kw];
            const float wb = w2[((o * 8 + 2 * c2 + 1) * 5 + kh) * 5 + kw];
            v = packh2(wa, wb);
        }
        s_w2p[k] = v;
    }
    // fc1 weights -> f16 j-pairs, rows padded to 49 (bank-spread + zero pads)
    for (int k = t; k < 1568; k += 256) {
        const int of = k / 49;
        const int j = k - 49 * of;
        uint32_t v = 0;
        if (j < 45) v = packh2(fc1w[of * 90 + 2 * j], fc1w[of * 90 + 2 * j + 1]);
        s_fc1wp[k] = v;
    }
    if (t < 64) s_h2p[t] = 0;   // zero (pads 45..47 must be 0 for fc1)
    __syncthreads();

    // ---- Stage B: conv1 (3->8, 7x7) + 2x2 maxpool + relu -> s_h1p (f16 c-pairs)
    // t = i*8 + o (proven map). acc init 0; bias folded after pooling.
    if (t < 176) {
        const int i = t >> 3, o = t & 7;
        float acc[22];
        #pragma unroll
        for (int j = 0; j < 22; ++j) acc[j] = 0.0f;

        for (int c = 0; c < 3; ++c) {
            #pragma unroll
            for (int kh = 0; kh < 7; ++kh) {
                const uint32_t* rowu =
                    (const uint32_t*)&s_imgh[(c * 28 + i + kh) * 40];
                uint32_t E[16];
                {
                    const uint4 a = ((const uint4*)rowu)[0];
                    const uint4 b = ((const uint4*)rowu)[1];
                    const uint4 cq = ((const uint4*)rowu)[2];
                    const uint4 d = ((const uint4*)rowu)[3];
                    E[0] = a.x;  E[1] = a.y;  E[2] = a.z;  E[3] = a.w;
                    E[4] = b.x;  E[5] = b.y;  E[6] = b.z;  E[7] = b.w;
                    E[8] = cq.x; E[9] = cq.y; E[10] = cq.z; E[11] = cq.w;
                    E[12] = d.x; E[13] = d.y; E[14] = d.z; E[15] = d.w;
                }
                uint32_t O[14];
                #pragma unroll
                for (int k = 0; k < 14; ++k)
                    O[k] = (E[k] >> 16) | (E[k + 1] << 16);

                const uint4 wq = *(const uint4*)&s_w1p[(o * 21 + c * 7 + kh) * 4];
                const half2_t wp0 = h2(wq.x), wp1 = h2(wq.y);
                const half2_t wp2 = h2(wq.z), wp3 = h2(wq.w);

                #pragma unroll
                for (int j = 0; j < 22; j += 2) {
                    const int b0 = j >> 1;
                    acc[j]     = FDOT2(h2(E[b0]),     wp0, acc[j]);
                    acc[j]     = FDOT2(h2(E[b0 + 1]), wp1, acc[j]);
                    acc[j]     = FDOT2(h2(E[b0 + 2]), wp2, acc[j]);
                    acc[j]     = FDOT2(h2(E[b0 + 3]), wp3, acc[j]);
                    acc[j + 1] = FDOT2(h2(O[b0]),     wp0, acc[j + 1]);
                    acc[j + 1] = FDOT2(h2(O[b0 + 1]), wp1, acc[j + 1]);
                    acc[j + 1] = FDOT2(h2(O[b0 + 2]), wp2, acc[j + 1]);
                    acc[j + 1] = FDOT2(h2(O[b0 + 3]), wp3, acc[j + 1]);
                }
            }
        }
        const float bias = b1[o];   // load overlapped with the loop above
        float hm[11];
        #pragma unroll
        for (int j = 0; j < 11; ++j) hm[j] = fmaxf(acc[2 * j], acc[2 * j + 1]);
        #pragma unroll
        for (int j = 0; j < 11; ++j) {
            float v = __shfl_xor(hm[j], 8);   // partner row i^1 = lane^8
            hm[j] = fmaxf(hm[j], v);
        }
        if ((i & 1) == 0) {
            const int c2 = o >> 1, hf = o & 1, u = i >> 1;
            _Float16* dst = ((_Float16*)s_h1p) + ((c2 * 11 + u) * 12) * 2 + hf;
            #pragma unroll
            for (int m = 0; m < 11; ++m)
                dst[2 * m] = (_Float16)fmaxf(hm[m] + bias, 0.0f);
        }
    }
    __syncthreads();

    // ---- Stage D: conv2 (8->10, 5x5) + 2x2 maxpool + relu -> s_h2p (f16)
    // 60 threads; ALL operands from LDS; channel-paired fdot2.
    if (t < 60) {
        const int o = t / 6, i = t - 6 * (t / 6);
        float acc2[6];
        #pragma unroll
        for (int j = 0; j < 6; ++j) acc2[j] = 0.0f;
        #pragma unroll
        for (int c2 = 0; c2 < 4; ++c2) {
            #pragma unroll
            for (int kh = 0; kh < 5; ++kh) {
                const uint32_t* row = &s_h1p[(c2 * 11 + i + kh) * 12];
                uint32_t E[12];
                {
                    const uint4 a = ((const uint4*)row)[0];
                    const uint4 b = ((const uint4*)row)[1];
                    const uint4 cq = ((const uint4*)row)[2];
                    E[0] = a.x;  E[1] = a.y;  E[2] = a.z;  E[3] = a.w;
                    E[4] = b.x;  E[5] = b.y;  E[6] = b.z;  E[7] = b.w;
                    E[8] = cq.x; E[9] = cq.y; E[10] = cq.z; E[11] = cq.w;
                }
                const uint32_t* wb = &s_w2p[((c2 * 5 + kh) * 10 + o) * 8];
                const uint4 wq = *(const uint4*)wb;
                const uint32_t w4 = wb[4];
                const half2_t wp0 = h2(wq.x), wp1 = h2(wq.y), wp2 = h2(wq.z),
                              wp3 = h2(wq.w), wp4 = h2(w4);
                #pragma unroll
                for (int j = 0; j < 6; ++j) {
                    float a = acc2[j];
                    a = FDOT2(h2(E[j]),     wp0, a);
                    a = FDOT2(h2(E[j + 1]), wp1, a);
                    a = FDOT2(h2(E[j + 2]), wp2, a);
                    a = FDOT2(h2(E[j + 3]), wp3, a);
                    a = FDOT2(h2(E[j + 4]), wp4, a);
                    acc2[j] = a;
                }
            }
        }
        const float bias = b2[o];
        float hp[3];
        #pragma unroll
        for (int q = 0; q < 3; ++q) hp[q] = fmaxf(acc2[2 * q], acc2[2 * q + 1]);
        #pragma unroll
        for (int q = 0; q < 3; ++q) {
            float v = __shfl_xor(hp[q], 1);   // partner i^1 = lane^1
            hp[q] = fmaxf(hp[q], v);
        }
        if ((i & 1) == 0) {
            #pragma unroll
            for (int q = 0; q < 3; ++q)
                ((_Float16*)s_h2p)[o * 9 + (i >> 1) * 3 + q] =
                    (_Float16)fmaxf(hp[q] + bias, 0.0f);
        }
    }
    __syncthreads();

    // ---- Stage F: fc1 (90->32) + relu; 32 outputs x 8 lanes, pure LDS fdot2
    {
        const int of = t >> 3, l = t & 7;
        float acc = 0.0f;
        const uint32_t* wr = &s_fc1wp[of * 49];
        #pragma unroll
        for (int m = 0; m < 6; ++m) {
            const int j = l + 8 * m;   // 0..47; pads 45..47 are zero
            acc = FDOT2(h2(s_h2p[j]), h2(wr[j]), acc);
        }
        acc += __shfl_xor(acc, 1);
        acc += __shfl_xor(acc, 2);
        acc += __shfl_xor(acc, 4);
        if (l == 0) s_fch[of] = fmaxf(acc + fc1b[of], 0.0f);
    }
    __syncthreads();

    // ---- Stage G: fc2 (32->6); 48 threads -> theta
    if (t < 48) {
        const int of = t >> 3, l = t & 7;
        float acc = 0.0f;
        const float* wr = &fc2w[of * 32];
        #pragma unroll
        for (int m = 0; m < 4; ++m) {
            int j = l + 8 * m;
            acc += s_fch[j] * wr[j];
        }
        acc += __shfl_xor(acc, 1);
        acc += __shfl_xor(acc, 2);
        acc += __shfl_xor(acc, 4);
        if (l == 0) theta_ws[(size_t)n * 6 + of] = acc + fc2b[of];
    }
}

__launch_bounds__(256)
__global__ void stn_sample_kernel(
    const float* __restrict__ x,
    const float* __restrict__ theta_ws,
    float* __restrict__ out)
{
    const int t = threadIdx.x;
    const int n = blockIdx.x;
    const float* tw = theta_ws + (size_t)n * 6;
    const float t00 = tw[0], t01 = tw[1], t02 = tw[2];
    const float t10 = tw[3], t11 = tw[4], t12 = tw[5];
    const float* img = x + (size_t)n * 2352;       // HWC
    float* outp = out + (size_t)n * 2352;

    for (int p = t; p < 784; p += 256) {
        int h = p / 28, w = p - 28 * h;
        float xs = (2.0f * w + 1.0f) * (1.0f / 28.0f) - 1.0f;
        float ys = (2.0f * h + 1.0f) * (1.0f / 28.0f) - 1.0f;
        float gx = t00 * xs + t01 * ys + t02;
        float gy = t10 * xs + t11 * ys + t12;
        float ix = ((gx + 1.0f) * 28.0f - 1.0f) * 0.5f;
        float iy = ((gy + 1.0f) * 28.0f - 1.0f) * 0.5f;
        float x0f = floorf(ix), y0f = floorf(iy);
        float wx1 = ix - x0f, wx0 = 1.0f - wx1;
        float wy1 = iy - y0f, wy0 = 1.0f - wy1;
        int x0 = (int)x0f, y0 = (int)y0f;
        int x1 = x0 + 1, y1 = y0 + 1;
        float fx0 = (x0 >= 0 && x0 < 28) ? 1.0f : 0.0f;
        float fx1 = (x1 >= 0 && x1 < 28) ? 1.0f : 0.0f;
        float fy0 = (y0 >= 0 && y0 < 28) ? 1.0f : 0.0f;
        float fy1 = (y1 >= 0 && y1 < 28) ? 1.0f : 0.0f;
        float w00 = wx0 * wy0 * fx0 * fy0;
        float w10 = wx1 * wy0 * fx1 * fy0;
        float w01 = wx0 * wy1 * fx0 * fy1;
        float w11 = wx1 * wy1 * fx1 * fy1;
        int cx0 = min(max(x0, 0), 27), cx1 = min(max(x1, 0), 27);
        int cy0 = min(max(y0, 0), 27), cy1 = min(max(y1, 0), 27);
        const float* p00 = img + (cy0 * 28 + cx0) * 3;
        const float* p10 = img + (cy0 * 28 + cx1) * 3;
        const float* p01 = img + (cy1 * 28 + cx0) * 3;
        const float* p11 = img + (cy1 * 28 + cx1) * 3;
        float* o3 = outp + 3 * p;
        #pragma unroll
        for (int c = 0; c < 3; ++c) {
            o3[c] = p00[c] * w00 + p10[c] * w10 + p01[c] * w01 + p11[c] * w11;
        }
    }
}

extern "C" void kernel_launch(void* const* d_in, const int* in_sizes, int n_in,
                              void* d_out, int out_size, void* d_ws, size_t ws_size,
                              hipStream_t stream) {
    const float* x     = (const float*)d_in[0];
    const float* w1    = (const float*)d_in[1];
    const float* b1    = (const float*)d_in[2];
    const float* w2    = (const float*)d_in[3];
    const float* b2    = (const float*)d_in[4];
    const float* fc1w  = (const float*)d_in[5];
    const float* fc1b  = (const float*)d_in[6];
    const float* fc2w  = (const float*)d_in[7];
    const float* fc2b  = (const float*)d_in[8];
    float* outp  = (float*)d_out;
    float* theta = (float*)d_ws;   // 16384*6 floats = 393 KB

    const int n_img = 64 * 256;  // b*n
    stn_loc_kernel<<<dim3(n_img), dim3(256), 0, stream>>>(
        x, w1, b1, w2, b2, fc1w, fc1b, fc2w, fc2b, theta);
    stn_sample_kernel<<<dim3(n_img), dim3(256), 0, stream>>>(x, theta, outp);
}

// Round 10
// 312.334 us; speedup vs baseline: 1.1178x; 1.1178x over previous
//
#include <hip/hip_runtime.h>

// STN round 10: 4 images per block. r5-r9 showed per-phase instruction diets
// don't move K1 (phase serialization dominates: conv2 ran on 60/256 threads,
// conv1 on 176/256, between barriers). Batch 4 images/block so every phase
// runs near-full lanes; per-phase bodies are r8's proven forms, unchanged.

typedef _Float16 half2_t __attribute__((ext_vector_type(2)));

static __device__ inline half2_t h2(uint32_t u) {
    union { uint32_t u; half2_t h; } cv; cv.u = u; return cv.h;
}
static __device__ inline uint32_t packh2(float a, float b) {
    union { half2_t h; uint32_t u; } cv;
    cv.h = (half2_t){(_Float16)a, (_Float16)b};
    return cv.u;
}

#if __has_builtin(__builtin_amdgcn_fdot2)
#define FDOT2(a, b, c) __builtin_amdgcn_fdot2((a), (b), (c), false)
#else
#define FDOT2(a, b, c) ((float)(a)[0] * (float)(b)[0] + (float)(a)[1] * (float)(b)[1] + (c))
#endif

__launch_bounds__(256, 4)
__global__ void stn_loc_kernel(
    const float* __restrict__ x,
    const float* __restrict__ w1, const float* __restrict__ b1,
    const float* __restrict__ w2, const float* __restrict__ b2,
    const float* __restrict__ fc1w, const float* __restrict__ fc1b,
    const float* __restrict__ fc2w, const float* __restrict__ fc2b,
    float* __restrict__ theta_ws)
{
    __shared__ __align__(16) _Float16 s_imgh[4][3 * 28 * 40];  // 26880 B
    __shared__ __align__(16) uint32_t s_w1p[8 * 21 * 4];       // 2688 B (shared)
    __shared__ __align__(16) float s_h1[4][8 * 11 * 12];       // 16896 B
    __shared__ float s_h2[4][90];
    __shared__ float s_fch[4][32];

    const int t = threadIdx.x;
    const int nb = blockIdx.x;                  // 4096 blocks, 4 images each

    // ---- Stage A: 4 images HWC fp32 -> LDS CHW f16 (+col pads), w1 -> pairs
    for (int im = 0; im < 4; ++im) {
        const float* img = x + ((size_t)(nb * 4 + im)) * 2352;
        for (int p = t; p < 784; p += 256) {
            const int h = p / 28, w = p - 28 * h;
            s_imgh[im][(0 * 28 + h) * 40 + w] = (_Float16)img[3 * p + 0];
            s_imgh[im][(1 * 28 + h) * 40 + w] = (_Float16)img[3 * p + 1];
            s_imgh[im][(2 * 28 + h) * 40 + w] = (_Float16)img[3 * p + 2];
        }
        for (int idx = t; idx < 504; idx += 256) {
            const int cc = idx / 168;
            const int rem = idx - 168 * cc;
            const int hh = rem / 6;
            const int kk = rem - 6 * hh;
            ((uint32_t*)s_imgh[im])[(((cc * 28 + hh) * 40) + 28 + 2 * kk) >> 1] = 0u;
        }
    }
    for (int idx = t; idx < 672; idx += 256) {
        const int o = idx / 84;  const int rem = idx - 84 * o;
        const int c = rem / 28;  const int r2 = rem - 28 * c;
        const int kh = r2 >> 2;  const int p = r2 & 3;
        const int k0 = 2 * p;
        const float* wbase = &w1[((o * 3 + c) * 7 + kh) * 7];
        const float wa = wbase[k0];
        const float wb = (k0 + 1 < 7) ? wbase[k0 + 1] : 0.0f;
        s_w1p[idx] = packh2(wa, wb);
    }
    __syncthreads();

    // ---- Stage B: conv1 + maxpool + relu, 704 units = 4 im x (22 rows x 8 ch)
    // unit u: im = u/176, r = u%176, i = r>>3, o = r&7. Pool partner u^8 is
    // same-image row i^1 (176*im has zero low nibble), same wave, same pass.
    for (int u = t; u < 704; u += 256) {
        const int im = u / 176;
        const int r  = u - 176 * im;
        const int i = r >> 3, o = r & 7;
        float acc[22];
        #pragma unroll
        for (int j = 0; j < 22; ++j) acc[j] = 0.0f;

        for (int c = 0; c < 3; ++c) {
            #pragma unroll
            for (int kh = 0; kh < 7; ++kh) {
                const uint32_t* rowu =
                    (const uint32_t*)&s_imgh[im][(c * 28 + i + kh) * 40];
                uint32_t E[16];
                {
                    const uint4 a = ((const uint4*)rowu)[0];
                    const uint4 b = ((const uint4*)rowu)[1];
                    const uint4 cq = ((const uint4*)rowu)[2];
                    const uint4 d = ((const uint4*)rowu)[3];
                    E[0] = a.x;  E[1] = a.y;  E[2] = a.z;  E[3] = a.w;
                    E[4] = b.x;  E[5] = b.y;  E[6] = b.z;  E[7] = b.w;
                    E[8] = cq.x; E[9] = cq.y; E[10] = cq.z; E[11] = cq.w;
                    E[12] = d.x; E[13] = d.y; E[14] = d.z; E[15] = d.w;
                }
                uint32_t O[14];
                #pragma unroll
                for (int k = 0; k < 14; ++k)
                    O[k] = (E[k] >> 16) | (E[k + 1] << 16);

                const uint4 wq = *(const uint4*)&s_w1p[(o * 21 + c * 7 + kh) * 4];
                const half2_t wp0 = h2(wq.x), wp1 = h2(wq.y);
                const half2_t wp2 = h2(wq.z), wp3 = h2(wq.w);

                #pragma unroll
                for (int j = 0; j < 22; j += 2) {
                    const int b0 = j >> 1;
                    acc[j]     = FDOT2(h2(E[b0]),     wp0, acc[j]);
                    acc[j]     = FDOT2(h2(E[b0 + 1]), wp1, acc[j]);
                    acc[j]     = FDOT2(h2(E[b0 + 2]), wp2, acc[j]);
                    acc[j]     = FDOT2(h2(E[b0 + 3]), wp3, acc[j]);
                    acc[j + 1] = FDOT2(h2(O[b0]),     wp0, acc[j + 1]);
                    acc[j + 1] = FDOT2(h2(O[b0 + 1]), wp1, acc[j + 1]);
                    acc[j + 1] = FDOT2(h2(O[b0 + 2]), wp2, acc[j + 1]);
                    acc[j + 1] = FDOT2(h2(O[b0 + 3]), wp3, acc[j + 1]);
                }
            }
        }
        const float bias = b1[o];
        float hm[11];
        #pragma unroll
        for (int j = 0; j < 11; ++j) hm[j] = fmaxf(acc[2 * j], acc[2 * j + 1]);
        #pragma unroll
        for (int j = 0; j < 11; ++j) {
            float v = __shfl_xor(hm[j], 8);   // partner: same im, row i^1
            hm[j] = fmaxf(hm[j], v);
        }
        if ((i & 1) == 0) {
            float* row = &s_h1[im][(o * 11 + (i >> 1)) * 12];
            #pragma unroll
            for (int j = 0; j < 11; ++j) row[j] = fmaxf(hm[j] + bias, 0.0f);
        }
    }
    __syncthreads();

    // ---- Stage D: conv2 + maxpool + relu, 240 threads = 4 im x 60
    if (t < 240) {
        const int im = t / 60;
        const int r = t - 60 * im;
        const int o = r / 6, i = r - 6 * (r / 6);
        float acc2[6];
        const float bias = b2[o];
        #pragma unroll
        for (int j = 0; j < 6; ++j) acc2[j] = bias;
        for (int c = 0; c < 8; ++c) {
            #pragma unroll
            for (int kh = 0; kh < 5; ++kh) {
                const float* hrow = &s_h1[im][(c * 11 + i + kh) * 12];
                float im2[12];
                #pragma unroll
                for (int qq = 0; qq < 3; ++qq) {
                    float4 v = ((const float4*)hrow)[qq];
                    im2[4 * qq + 0] = v.x; im2[4 * qq + 1] = v.y;
                    im2[4 * qq + 2] = v.z; im2[4 * qq + 3] = v.w;
                }
                const float* wr = &w2[(o * 8 + c) * 25 + kh * 5];
                float wv[5];
                #pragma unroll
                for (int qq = 0; qq < 5; ++qq) wv[qq] = wr[qq];
                #pragma unroll
                for (int kw = 0; kw < 5; ++kw) {
                    #pragma unroll
                    for (int j = 0; j < 6; ++j)
                        acc2[j] += im2[j + kw] * wv[kw];
                }
            }
        }
        float hp[3];
        #pragma unroll
        for (int qq = 0; qq < 3; ++qq) hp[qq] = fmaxf(acc2[2 * qq], acc2[2 * qq + 1]);
        #pragma unroll
        for (int qq = 0; qq < 3; ++qq) {
            float v = __shfl_xor(hp[qq], 1);   // partner i^1 = t^1 (60*im even)
            hp[qq] = fmaxf(hp[qq], v);
        }
        if ((i & 1) == 0) {
            #pragma unroll
            for (int qq = 0; qq < 3; ++qq)
                s_h2[im][o * 9 + (i >> 1) * 3 + qq] = fmaxf(hp[qq], 0.0f);
        }
    }
    __syncthreads();

    // ---- Stage F: fc1 (90->32) + relu; 256 threads = 4 im x 32 of x 2 lanes
    {
        const int im = t >> 6;
        const int of = (t >> 1) & 31;
        const int l = t & 1;
        float acc = 0.0f;
        const float* wr = &fc1w[of * 90];
        #pragma unroll
        for (int j = 0; j < 45; ++j) {
            const int jj = l + 2 * j;
            acc += s_h2[im][jj] * wr[jj];
        }
        acc += __shfl_xor(acc, 1);
        if (l == 0) s_fch[im][of] = fmaxf(acc + fc1b[of], 0.0f);
    }
    __syncthreads();

    // ---- Stage G: fc2 (32->6); 192 threads = 4 im x 6 of x 8 lanes
    if (t < 192) {
        const int im = t / 48;
        const int r = t - 48 * im;
        const int of = r >> 3, l = r & 7;
        float acc = 0.0f;
        const float* wr = &fc2w[of * 32];
        #pragma unroll
        for (int m = 0; m < 4; ++m) {
            const int j = l + 8 * m;
            acc += s_fch[im][j] * wr[j];
        }
        acc += __shfl_xor(acc, 1);
        acc += __shfl_xor(acc, 2);
        acc += __shfl_xor(acc, 4);
        if (l == 0) theta_ws[((size_t)(nb * 4 + im)) * 6 + of] = acc + fc2b[of];
    }
}

__launch_bounds__(256)
__global__ void stn_sample_kernel(
    const float* __restrict__ x,
    const float* __restrict__ theta_ws,
    float* __restrict__ out)
{
    const int t = threadIdx.x;
    const int n = blockIdx.x;
    const float* tw = theta_ws + (size_t)n * 6;
    const float t00 = tw[0], t01 = tw[1], t02 = tw[2];
    const float t10 = tw[3], t11 = tw[4], t12 = tw[5];
    const float* img = x + (size_t)n * 2352;       // HWC
    float* outp = out + (size_t)n * 2352;

    for (int p = t; p < 784; p += 256) {
        int h = p / 28, w = p - 28 * h;
        float xs = (2.0f * w + 1.0f) * (1.0f / 28.0f) - 1.0f;
        float ys = (2.0f * h + 1.0f) * (1.0f / 28.0f) - 1.0f;
        float gx = t00 * xs + t01 * ys + t02;
        float gy = t10 * xs + t11 * ys + t12;
        float ix = ((gx + 1.0f) * 28.0f - 1.0f) * 0.5f;
        float iy = ((gy + 1.0f) * 28.0f - 1.0f) * 0.5f;
        float x0f = floorf(ix), y0f = floorf(iy);
        float wx1 = ix - x0f, wx0 = 1.0f - wx1;
        float wy1 = iy - y0f, wy0 = 1.0f - wy1;
        int x0 = (int)x0f, y0 = (int)y0f;
        int x1 = x0 + 1, y1 = y0 + 1;
        float fx0 = (x0 >= 0 && x0 < 28) ? 1.0f : 0.0f;
        float fx1 = (x1 >= 0 && x1 < 28) ? 1.0f : 0.0f;
        float fy0 = (y0 >= 0 && y0 < 28) ? 1.0f : 0.0f;
        float fy1 = (y1 >= 0 && y1 < 28) ? 1.0f : 0.0f;
        float w00 = wx0 * wy0 * fx0 * fy0;
        float w10 = wx1 * wy0 * fx1 * fy0;
        float w01 = wx0 * wy1 * fx0 * fy1;
        float w11 = wx1 * wy1 * fx1 * fy1;
        int cx0 = min(max(x0, 0), 27), cx1 = min(max(x1, 0), 27);
        int cy0 = min(max(y0, 0), 27), cy1 = min(max(y1, 0), 27);
        const float* p00 = img + (cy0 * 28 + cx0) * 3;
        const float* p10 = img + (cy0 * 28 + cx1) * 3;
        const float* p01 = img + (cy1 * 28 + cx0) * 3;
        const float* p11 = img + (cy1 * 28 + cx1) * 3;
        float* o3 = outp + 3 * p;
        #pragma unroll
        for (int c = 0; c < 3; ++c) {
            o3[c] = p00[c] * w00 + p10[c] * w10 + p01[c] * w01 + p11[c] * w11;
        }
    }
}

extern "C" void kernel_launch(void* const* d_in, const int* in_sizes, int n_in,
                              void* d_out, int out_size, void* d_ws, size_t ws_size,
                              hipStream_t stream) {
    const float* x     = (const float*)d_in[0];
    const float* w1    = (const float*)d_in[1];
    const float* b1    = (const float*)d_in[2];
    const float* w2    = (const float*)d_in[3];
    const float* b2    = (const float*)d_in[4];
    const float* fc1w  = (const float*)d_in[5];
    const float* fc1b  = (const float*)d_in[6];
    const float* fc2w  = (const float*)d_in[7];
    const float* fc2b  = (const float*)d_in[8];
    float* outp  = (float*)d_out;
    float* theta = (float*)d_ws;   // 16384*6 floats = 393 KB

    const int n_img = 64 * 256;  // b*n
    stn_loc_kernel<<<dim3(n_img / 4), dim3(256), 0, stream>>>(
        x, w1, b1, w2, b2, fc1w, fc1b, fc2w, fc2b, theta);
    stn_sample_kernel<<<dim3(n_img), dim3(256), 0, stream>>>(x, theta, outp);
}